// Round 6
// baseline (196.447 us; speedup 1.0000x reference)
//
#include <hip/hip_runtime.h>

// PINN fused: u, du/dx0, d2u/dx0^2 of tanh-MLP (2->256->256->256->1), fp32 in/out.
// Round 12: back to the known-correct R10 base (slot-paired sub-tiles, 142us;
// R11's wave-group variant failed d2u with an input-scaling error - its one
// numeric delta, the exp2f builtin in fast_tanh, is removed outright).
// Single new variable: T19 sched_group_barrier inside MSTEP to FORCE the
// MFMA<->VALU interleave the compiler refused to emit (R10 proved statement-
// level pairing still SUMS: MFMA 46us + VALU 62us busy, both invariant).
// Per kc-step forced layout: [3xDS_READ][4xVMEM_READ][{1xMFMA,4xVALU}x12] so
// the paired phase's tanh/pack VALU issues in the matrix-pipe shadow.
//   slot1: L1(A)            slot4: M3(A) || E2(B)
//   slot2: M2(A) || L1(B)   slot5: M3(B) || E3(A)
//   slot3: M2(B) || E2(A)   slot6: E3(B)
// SGB is a scheduling directive only - dependencies still enforced, so
// correctness is identical to R10 by construction.

#define HID 256
#define TM  32

typedef _Float16 half8 __attribute__((ext_vector_type(8)));
typedef _Float16 half4 __attribute__((ext_vector_type(4)));
typedef float    f32x4 __attribute__((ext_vector_type(4)));

#define MFMA16 __builtin_amdgcn_mfma_f32_16x16x32_f16
#define SGB    __builtin_amdgcn_sched_group_barrier

__device__ __forceinline__ float fast_tanh(float z) {
    // tanh(z) = 1 - 2/(exp(2z)+1); saturates correctly at +-inf
    const float e = __expf(2.0f * z);
#if __has_builtin(__builtin_amdgcn_rcpf)
    const float r = __builtin_amdgcn_rcpf(e + 1.0f);
#else
    const float r = 1.0f / (e + 1.0f);
#endif
    return fmaf(-2.0f, r, 1.0f);
}

// Pack W2/W3 (fp32 [256][256], row=k, col=n) into MFMA A-fragment order for W^T,
// fp16 (hi) only.  Layout: elem = ((kc*16 + strip)*64 + lane)*8 + j  (strip =
// wave*4 + nt), so a wave's 4 strips per kc are imm-offset addressable.
// frag value (kc, strip, lane, j) = W[kc*32 + (lane>>4)*8 + j][strip*16 + (lane&15)]
// ws layout (f16 elems): W2 @ 0, W3 @ 65536.  (256KB total)
__global__ __launch_bounds__(256) void prep_w(const float* __restrict__ W2,
                                              const float* __restrict__ W3,
                                              _Float16* __restrict__ wsf) {
    const int t = blockIdx.x * 256 + threadIdx.x;     // 0..16383
    const float* __restrict__ W = (t >> 13) ? W3 : W2;
    _Float16* dst = wsf + (size_t)(t >> 13) * 65536;
    const int r     = t & 8191;
    const int kc    = r >> 10;          // 0..7
    const int strip = (r >> 6) & 15;    // 0..15
    const int lane  = r & 63;
    const int row   = kc * 32 + ((lane >> 4) << 3);
    const int col   = strip * 16 + (lane & 15);
    half8 vh;
    #pragma unroll
    for (int j = 0; j < 8; ++j)
        vh[j] = (_Float16)W[(size_t)(row + j) * HID + col];
    *(half8*)&dst[(size_t)r * 8] = vh;
}

// ---- phase building blocks (macros so all indices stay compile-time) ----

// one kc step of a 16-sample sub-tile: 3 A-frag LDS reads + 4 W-frag loads +
// 12 MFMA, followed by the T19 directive tail that interleaves 4 VALU (from
// the paired phase in the same scheduling region) behind every MFMA.
#define MSTEP(Abase, Wl, acc, kc) do {                                          \
    const _Float16* __restrict__ Ap_ = (Abase) + ml * 256                       \
                                     + (((((kc) << 2) | hi) ^ rk) << 3);        \
    const half8 a0_ = *(const half8*)&Ap_[0];                                   \
    const half8 a1_ = *(const half8*)&Ap_[4096];                                \
    const half8 a2_ = *(const half8*)&Ap_[8192];                                \
    const _Float16* __restrict__ Wk_ = (Wl) + ((kc) << 13);                     \
    const half8 w0_ = *(const half8*)&Wk_[0];                                   \
    const half8 w1_ = *(const half8*)&Wk_[512];                                 \
    const half8 w2_ = *(const half8*)&Wk_[1024];                                \
    const half8 w3_ = *(const half8*)&Wk_[1536];                                \
    __builtin_amdgcn_s_setprio(1);                                              \
    acc[0][0] = MFMA16(w0_, a0_, acc[0][0], 0, 0, 0);                           \
    acc[1][0] = MFMA16(w0_, a1_, acc[1][0], 0, 0, 0);                           \
    acc[2][0] = MFMA16(w0_, a2_, acc[2][0], 0, 0, 0);                           \
    acc[0][1] = MFMA16(w1_, a0_, acc[0][1], 0, 0, 0);                           \
    acc[1][1] = MFMA16(w1_, a1_, acc[1][1], 0, 0, 0);                           \
    acc[2][1] = MFMA16(w1_, a2_, acc[2][1], 0, 0, 0);                           \
    acc[0][2] = MFMA16(w2_, a0_, acc[0][2], 0, 0, 0);                           \
    acc[1][2] = MFMA16(w2_, a1_, acc[1][2], 0, 0, 0);                           \
    acc[2][2] = MFMA16(w2_, a2_, acc[2][2], 0, 0, 0);                           \
    acc[0][3] = MFMA16(w3_, a0_, acc[0][3], 0, 0, 0);                           \
    acc[1][3] = MFMA16(w3_, a1_, acc[1][3], 0, 0, 0);                           \
    acc[2][3] = MFMA16(w3_, a2_, acc[2][3], 0, 0, 0);                           \
    __builtin_amdgcn_s_setprio(0);                                              \
    SGB(0x100, 3, 0);      /* 3x ds_read_b128 (A frags) */                      \
    SGB(0x020, 4, 0);      /* 4x global weight loads    */                      \
    _Pragma("unroll")                                                           \
    for (int g_ = 0; g_ < 12; ++g_) {                                           \
        SGB(0x008, 1, 0);  /* 1x MFMA                   */                      \
        SGB(0x002, 4, 0);  /* 4x VALU from paired phase */                      \
    }                                                                           \
} while (0)

// layer-1 for 4 units (chunk c=0..3) of sample mL, swizzled write into dst tile
#define L1_CHUNK(dst, xv, c) do {                                               \
    const int n0_ = k0 + ((c) << 2);                                            \
    const f32x4 w0_ = *(const f32x4*)&W1[n0_];                                  \
    const f32x4 w1_ = *(const f32x4*)&W1[HID + n0_];                            \
    const f32x4 bb_ = *(const f32x4*)&b1[n0_];                                  \
    half4 h0_, h1_, h2_;                                                        \
    _Pragma("unroll")                                                           \
    for (int r = 0; r < 4; ++r) {                                               \
        const float z_  = fmaf((xv).x, w0_[r], fmaf((xv).y, w1_[r], bb_[r]));   \
        const float a_  = fast_tanh(z_);                                        \
        const float sN_ = 1.0f - a_ * a_;                                       \
        const float ad_  = sN_ * w0_[r];                                        \
        const float add_ = -2.0f * a_ * ad_ * w0_[r];                           \
        h0_[r] = (_Float16)a_; h1_[r] = (_Float16)ad_; h2_[r] = (_Float16)add_; \
    }                                                                           \
    const int go_ = (((n0_ >> 3) ^ (mL & 7)) << 3) + (n0_ & 7);                 \
    _Float16* dp_ = &(dst)[mL * 256 + go_];                                     \
    *(half4*)&dp_[0]    = h0_;                                                  \
    *(half4*)&dp_[4096] = h1_;                                                  \
    *(half4*)&dp_[8192] = h2_;                                                  \
} while (0)

// layer-2 epilogue for one nt strip (4 units): tanh chain + swizzled LDS write
#define E2_CHUNK(dst, acc, nt) do {                                             \
    const int ub_ = (wave << 6) + ((nt) << 4) + u4;                             \
    const f32x4 bb_ = *(const f32x4*)&b2[ub_];                                  \
    const int gs_ = (((ub_ >> 3) ^ rk) << 3) + (u4 & 4);                        \
    half4 h0_, h1_, h2_;                                                        \
    _Pragma("unroll")                                                           \
    for (int r = 0; r < 4; ++r) {                                               \
        const float z_   = acc[0][nt][r] + bb_[r];                              \
        const float a_   = fast_tanh(z_);                                       \
        const float sN_  = 1.0f - a_ * a_;                                      \
        const float zd_  = acc[1][nt][r];                                       \
        const float zdd_ = acc[2][nt][r];                                       \
        const float ad_  = sN_ * zd_;                                           \
        const float add_ = fmaf(sN_, zdd_, -2.0f * a_ * ad_ * zd_);             \
        h0_[r] = (_Float16)a_; h1_[r] = (_Float16)ad_; h2_[r] = (_Float16)add_; \
    }                                                                           \
    _Float16* dp_ = &(dst)[ml * 256 + gs_];                                     \
    *(half4*)&dp_[0]    = h0_;                                                  \
    *(half4*)&dp_[4096] = h1_;                                                  \
    *(half4*)&dp_[8192] = h2_;                                                  \
} while (0)

// layer-3 epilogue for one nt strip fused with W4 dot (registers only)
#define E3_CHUNK(acc, pd, nt) do {                                              \
    const int ub_ = (wave << 6) + ((nt) << 4) + u4;                             \
    const f32x4 bb_ = *(const f32x4*)&b3[ub_];                                  \
    const f32x4 w4_ = *(const f32x4*)&W4[ub_];                                  \
    _Pragma("unroll")                                                           \
    for (int r = 0; r < 4; ++r) {                                               \
        const float z_   = acc[0][nt][r] + bb_[r];                              \
        const float a_   = fast_tanh(z_);                                       \
        const float sN_  = 1.0f - a_ * a_;                                      \
        const float zd_  = acc[1][nt][r];                                       \
        const float zdd_ = acc[2][nt][r];                                       \
        const float ad_  = sN_ * zd_;                                           \
        const float add_ = fmaf(sN_, zdd_, -2.0f * a_ * ad_ * zd_);             \
        pd[0] = fmaf(a_,   w4_[r], pd[0]);                                      \
        pd[1] = fmaf(ad_,  w4_[r], pd[1]);                                      \
        pd[2] = fmaf(add_, w4_[r], pd[2]);                                      \
    }                                                                           \
} while (0)

#define ZERO_ACC(acc) do {                                                      \
    _Pragma("unroll")                                                           \
    for (int s_ = 0; s_ < 3; ++s_)                                              \
        _Pragma("unroll")                                                       \
        for (int n_ = 0; n_ < 4; ++n_)                                          \
            acc[s_][n_] = (f32x4){0.f, 0.f, 0.f, 0.f};                          \
} while (0)

__global__ __launch_bounds__(256, 2) void pinn_mfma(
    const float* __restrict__ x,
    const float* __restrict__ W1, const float* __restrict__ b1,
    const float* __restrict__ b2, const float* __restrict__ b3,
    const float* __restrict__ W4, const float* __restrict__ b4,
    const _Float16* __restrict__ wsf,
    float* __restrict__ out, int B)
{
    // Two sub-tile A-buffers: 3 streams x 16 rows x 256 elems fp16 each,
    // 16B-granule XOR swizzle: elem(s,row,e) at s*4096 + row*256
    //                                         + (((e>>3) ^ (row&7))<<3) + (e&7)
    __shared__ __align__(16) _Float16 AhiA[3 * 16 * 256];   // 24 KB
    __shared__ __align__(16) _Float16 AhiB[3 * 16 * 256];   // 24 KB
    __shared__ float psum[2][4][3][16];                     // 1.5 KB

    const int tid  = threadIdx.x;
    const int s0   = blockIdx.x * TM;
    const int lane = tid & 63;
    const int wave = tid >> 6;          // 0..3

    // L1 mapping: thread owns sample mL (tile-local), 16 units k0..k0+15
    const int mL = tid & 15;
    const int k0 = (tid >> 4) << 4;
    // MFMA / epilogue mapping
    const int ml = lane & 15;            // B/D col = sample
    const int hi = lane >> 4;            // 0..3
    const int rk = ml & 7;               // swizzle key
    const int u4 = hi << 2;

    const float2 xA = *(const float2*)&x[(size_t)(s0 + mL) * 2];
    const float2 xB = *(const float2*)&x[(size_t)(s0 + 16 + mL) * 2];

    const _Float16* __restrict__ W2l = wsf + (wave << 11) + (lane << 3);
    const _Float16* __restrict__ W3l = W2l + 65536;

    f32x4 accA[3][4], accB[3][4];

    // ---- slot 1: L1(A) ----
    L1_CHUNK(AhiA, xA, 0); L1_CHUNK(AhiA, xA, 1);
    L1_CHUNK(AhiA, xA, 2); L1_CHUNK(AhiA, xA, 3);
    __syncthreads();

    // ---- slot 2: M2(A) || L1(B) ----
    ZERO_ACC(accA);
    MSTEP(AhiA, W2l, accA, 0); L1_CHUNK(AhiB, xB, 0); MSTEP(AhiA, W2l, accA, 1);
    MSTEP(AhiA, W2l, accA, 2); L1_CHUNK(AhiB, xB, 1); MSTEP(AhiA, W2l, accA, 3);
    MSTEP(AhiA, W2l, accA, 4); L1_CHUNK(AhiB, xB, 2); MSTEP(AhiA, W2l, accA, 5);
    MSTEP(AhiA, W2l, accA, 6); L1_CHUNK(AhiB, xB, 3); MSTEP(AhiA, W2l, accA, 7);
    __syncthreads();   // A-reads done (E2 will overwrite AhiA); AhiB visible

    // ---- slot 3: M2(B) || E2(A) ----
    ZERO_ACC(accB);
    MSTEP(AhiB, W2l, accB, 0); E2_CHUNK(AhiA, accA, 0); MSTEP(AhiB, W2l, accB, 1);
    MSTEP(AhiB, W2l, accB, 2); E2_CHUNK(AhiA, accA, 1); MSTEP(AhiB, W2l, accB, 3);
    MSTEP(AhiB, W2l, accB, 4); E2_CHUNK(AhiA, accA, 2); MSTEP(AhiB, W2l, accB, 5);
    MSTEP(AhiB, W2l, accB, 6); E2_CHUNK(AhiA, accA, 3); MSTEP(AhiB, W2l, accB, 7);
    __syncthreads();   // B-reads done; new AhiA visible

    // ---- slot 4: M3(A) || E2(B) ----
    ZERO_ACC(accA);
    MSTEP(AhiA, W3l, accA, 0); E2_CHUNK(AhiB, accB, 0); MSTEP(AhiA, W3l, accA, 1);
    MSTEP(AhiA, W3l, accA, 2); E2_CHUNK(AhiB, accB, 1); MSTEP(AhiA, W3l, accA, 3);
    MSTEP(AhiA, W3l, accA, 4); E2_CHUNK(AhiB, accB, 2); MSTEP(AhiA, W3l, accA, 5);
    MSTEP(AhiA, W3l, accA, 6); E2_CHUNK(AhiB, accB, 3); MSTEP(AhiA, W3l, accA, 7);
    __syncthreads();   // new AhiB visible

    // ---- slot 5: M3(B) || E3(A) ----
    ZERO_ACC(accB);
    float pdA[3] = {0.f, 0.f, 0.f};
    MSTEP(AhiB, W3l, accB, 0); E3_CHUNK(accA, pdA, 0); MSTEP(AhiB, W3l, accB, 1);
    MSTEP(AhiB, W3l, accB, 2); E3_CHUNK(accA, pdA, 1); MSTEP(AhiB, W3l, accB, 3);
    MSTEP(AhiB, W3l, accB, 4); E3_CHUNK(accA, pdA, 2); MSTEP(AhiB, W3l, accB, 5);
    MSTEP(AhiB, W3l, accB, 6); E3_CHUNK(accA, pdA, 3); MSTEP(AhiB, W3l, accB, 7);
    // finish E3(A): butterfly over lanes {ml, ml+16, ml+32, ml+48}
    #pragma unroll
    for (int s = 0; s < 3; ++s) {
        pdA[s] += __shfl_xor(pdA[s], 16, 64);
        pdA[s] += __shfl_xor(pdA[s], 32, 64);
    }
    if (lane < 16) {
        #pragma unroll
        for (int s = 0; s < 3; ++s) psum[0][wave][s][lane] = pdA[s];
    }

    // ---- slot 6: E3(B) ----
    float pdB[3] = {0.f, 0.f, 0.f};
    E3_CHUNK(accB, pdB, 0); E3_CHUNK(accB, pdB, 1);
    E3_CHUNK(accB, pdB, 2); E3_CHUNK(accB, pdB, 3);
    #pragma unroll
    for (int s = 0; s < 3; ++s) {
        pdB[s] += __shfl_xor(pdB[s], 16, 64);
        pdB[s] += __shfl_xor(pdB[s], 32, 64);
    }
    if (lane < 16) {
        #pragma unroll
        for (int s = 0; s < 3; ++s) psum[1][wave][s][lane] = pdB[s];
    }
    __syncthreads();

    if (tid < 96) {
        const int s  = tid >> 5;         // 0:u 1:du 2:d2u
        const int m  = tid & 31;         // sample within TM=32
        const int t  = m >> 4;           // sub-tile
        const int mm = m & 15;
        float v = psum[t][0][s][mm] + psum[t][1][s][mm]
                + psum[t][2][s][mm] + psum[t][3][s][mm];
        if (s == 0) v += b4[0];
        out[(size_t)s * B + s0 + m] = v;
    }
}

extern "C" void kernel_launch(void* const* d_in, const int* in_sizes, int n_in,
                              void* d_out, int out_size, void* d_ws, size_t ws_size,
                              hipStream_t stream) {
    const float* x  = (const float*)d_in[0];
    const float* W1 = (const float*)d_in[1];
    const float* b1 = (const float*)d_in[2];
    const float* W2 = (const float*)d_in[3];
    const float* b2 = (const float*)d_in[4];
    const float* W3 = (const float*)d_in[5];
    const float* b3 = (const float*)d_in[6];
    const float* W4 = (const float*)d_in[7];
    const float* b4 = (const float*)d_in[8];
    float* out = (float*)d_out;

    const int B = in_sizes[0] / 2;      // x is (B, 2)

    prep_w<<<64, 256, 0, stream>>>(W2, W3, (_Float16*)d_ws);
    pinn_mfma<<<B / TM, 256, 0, stream>>>(x, W1, b1, b2, b3, W4, b4,
                                          (const _Float16*)d_ws, out, B);
}

// Round 7
// 193.417 us; speedup vs baseline: 1.0157x; 1.0157x over previous
//
#include <hip/hip_runtime.h>

// PINN fused: u, du/dx0, d2u/dx0^2 of tanh-MLP (2->256->256->256->1), fp32 in/out.
// Round 13: retry wave-group phase stagger with R9's proven tanh (R12 showed
// T19/SGB is null and m253 says within-wave MFMA||VALU never overlaps; m114
// says cross-wave DOES. Six rounds establish MFMA 46us + VALU 63us SUM because
// barrier-locked blocks convoy. The stagger anti-phases wave w vs w+4 on the
// same SIMD by construction:)
//   slot0: A:L1        slot2: A:E2, B:M2   slot4: A:E3, B:M3+E3
//   slot1: A:M2, B:L1  slot3: A:M3, B:E2
// R11 (same structure) failed d2u with race-like signature; its ONLY delta vs
// the passing R9 phase bodies was the __builtin_amdgcn_exp2f tanh. This round
// = stagger structure + byte-identical R9 phases + R9 __expf tanh.
//   - 512 thr / 8 waves: grp0 = waves 0-3 (tile A, samples 0-15),
//     grp1 = waves 4-7 (tile B, samples 16-31), one slot behind.
//   - LDS 2x24KB + 1.5KB psum = 49.5KB; __launch_bounds__(512,4).

#define HID 256
#define TM  32

typedef _Float16 half8 __attribute__((ext_vector_type(8)));
typedef _Float16 half4 __attribute__((ext_vector_type(4)));
typedef float    f32x4 __attribute__((ext_vector_type(4)));

#define MFMA16 __builtin_amdgcn_mfma_f32_16x16x32_f16

__device__ __forceinline__ float fast_tanh(float z) {
    // tanh(z) = 1 - 2/(exp(2z)+1); saturates correctly at +-inf  (R9-proven)
    const float e = __expf(2.0f * z);
#if __has_builtin(__builtin_amdgcn_rcpf)
    const float r = __builtin_amdgcn_rcpf(e + 1.0f);
#else
    const float r = 1.0f / (e + 1.0f);
#endif
    return fmaf(-2.0f, r, 1.0f);
}

// Pack W2/W3 (fp32 [256][256], row=k, col=n) into MFMA A-fragment order for W^T,
// fp16 (hi) only.  Layout: elem = ((kc*16 + strip)*64 + lane)*8 + j  (strip =
// w4*4 + nt), so a wave's 4 strips per kc are imm-offset addressable.
// frag value (kc, strip, lane, j) = W[kc*32 + (lane>>4)*8 + j][strip*16 + (lane&15)]
// ws layout (f16 elems): W2 @ 0, W3 @ 65536.  (256KB total)
__global__ __launch_bounds__(256) void prep_w(const float* __restrict__ W2,
                                              const float* __restrict__ W3,
                                              _Float16* __restrict__ wsf) {
    const int t = blockIdx.x * 256 + threadIdx.x;     // 0..16383
    const float* __restrict__ W = (t >> 13) ? W3 : W2;
    _Float16* dst = wsf + (size_t)(t >> 13) * 65536;
    const int r     = t & 8191;
    const int kc    = r >> 10;          // 0..7
    const int strip = (r >> 6) & 15;    // 0..15
    const int lane  = r & 63;
    const int row   = kc * 32 + ((lane >> 4) << 3);
    const int col   = strip * 16 + (lane & 15);
    half8 vh;
    #pragma unroll
    for (int j = 0; j < 8; ++j)
        vh[j] = (_Float16)W[(size_t)(row + j) * HID + col];
    *(half8*)&dst[(size_t)r * 8] = vh;
}

__global__ __launch_bounds__(512, 4) void pinn_mfma(
    const float* __restrict__ x,
    const float* __restrict__ W1, const float* __restrict__ b1,
    const float* __restrict__ b2, const float* __restrict__ b3,
    const float* __restrict__ W4, const float* __restrict__ b4,
    const _Float16* __restrict__ wsf,
    float* __restrict__ out, int B)
{
    // per-group A-tile: 3 streams x 16 rows x 256 elems fp16, 16B-granule XOR
    // swizzle: elem(s,row,e) at s*4096 + row*256 + (((e>>3)^(row&7))<<3)+(e&7)
    __shared__ __align__(16) _Float16 AhiA[3 * 16 * 256];   // 24 KB (tile A)
    __shared__ __align__(16) _Float16 AhiB[3 * 16 * 256];   // 24 KB (tile B)
    __shared__ float psum[2][4][3][16];                     // 1.5 KB

    const int tid  = threadIdx.x;
    const int lane = tid & 63;
    const int wave = tid >> 6;          // 0..7
    const int grp  = wave >> 2;         // 0: tile A, 1: tile B (SIMD = wave&3)
    const int w4   = wave & 3;          // wave within group

    _Float16* __restrict__ Ahi = grp ? AhiB : AhiA;

    // ---- L1 mapping (per group: 256 threads = 16 samples x 16-unit chunks) ----
    const int ltid = tid & 255;
    const int mL   = ltid & 15;
    const int k0   = (ltid >> 4) << 4;                 // 0,16,...,240
    // ---- MFMA / epilogue mapping (per group, R9-identical) ----
    const int ml = lane & 15;            // B/D col = sample within group tile
    const int hi = lane >> 4;            // 0..3
    const int rk = ml & 7;               // swizzle key
    const int u4 = hi << 2;              // D-row sub-offset (unit)
    const _Float16* __restrict__ Arow = &Ahi[ml * 256];

    const float2 xv = *(const float2*)&x[(size_t)(blockIdx.x * TM + grp * 16 + mL) * 2];

    // per-wave weight base (strips w4*4+nt): + layer*65536 + kc*8192 + nt*512
    const _Float16* __restrict__ W2l = wsf + (w4 << 11) + (lane << 3);
    const _Float16* __restrict__ W3l = W2l + 65536;

    f32x4 acc[3][4];                     // [stream][nt]

    // =========== phase bodies (R9-identical, as lambdas over this scope) =====
    auto L1_PHASE = [&]() {
        half8 vh[3][2];
        #pragma unroll
        for (int q = 0; q < 2; ++q) {
            #pragma unroll
            for (int h = 0; h < 2; ++h) {
                const int n = k0 + q * 8 + h * 4;
                const f32x4 w0 = *(const f32x4*)&W1[n];
                const f32x4 w1 = *(const f32x4*)&W1[HID + n];
                const f32x4 bb = *(const f32x4*)&b1[n];
                #pragma unroll
                for (int r = 0; r < 4; ++r) {
                    const float z  = fmaf(xv.x, w0[r], fmaf(xv.y, w1[r], bb[r]));
                    const float a  = fast_tanh(z);
                    const float sN = 1.0f - a * a;
                    const float ad  = sN * w0[r];
                    const float add = -2.0f * a * ad * w0[r];
                    vh[0][q][h * 4 + r] = (_Float16)a;
                    vh[1][q][h * 4 + r] = (_Float16)ad;
                    vh[2][q][h * 4 + r] = (_Float16)add;
                }
            }
        }
        const int rkm = mL & 7;
        const int g0w = k0 >> 3;
        #pragma unroll
        for (int s = 0; s < 3; ++s)
            #pragma unroll
            for (int q = 0; q < 2; ++q)
                *(half8*)&Ahi[s * 4096 + mL * 256 + (((g0w + q) ^ rkm) << 3)] = vh[s][q];
    };

    auto MLOOP = [&](const _Float16* __restrict__ Wl) {
        #pragma unroll
        for (int s = 0; s < 3; ++s)
            #pragma unroll
            for (int nt = 0; nt < 4; ++nt)
                acc[s][nt] = (f32x4){0.f, 0.f, 0.f, 0.f};
        #pragma unroll
        for (int kc = 0; kc < 8; ++kc) {
            const _Float16* __restrict__ Ap =
                Arow + ((((kc << 2) | hi) ^ rk) << 3);
            const half8 af0 = *(const half8*)&Ap[0];
            const half8 af1 = *(const half8*)&Ap[4096];
            const half8 af2 = *(const half8*)&Ap[8192];
            const _Float16* __restrict__ Wk = Wl + (kc << 13);
            half8 wf[4];
            #pragma unroll
            for (int nt = 0; nt < 4; ++nt)
                wf[nt] = *(const half8*)&Wk[nt << 9];
            __builtin_amdgcn_s_setprio(1);
            #pragma unroll
            for (int nt = 0; nt < 4; ++nt) {
                acc[0][nt] = MFMA16(wf[nt], af0, acc[0][nt], 0, 0, 0);
                acc[1][nt] = MFMA16(wf[nt], af1, acc[1][nt], 0, 0, 0);
                acc[2][nt] = MFMA16(wf[nt], af2, acc[2][nt], 0, 0, 0);
            }
            __builtin_amdgcn_s_setprio(0);
        }
    };

    auto E2_PHASE = [&]() {
        #pragma unroll
        for (int nt = 0; nt < 4; ++nt) {
            const int ub  = (w4 << 6) + (nt << 4) + u4;    // 4 consecutive units
            const f32x4 bb = *(const f32x4*)&b2[ub];
            const int gsw = (((ub >> 3) ^ rk) << 3) + (u4 & 4);
            half4 hv[3];
            #pragma unroll
            for (int r = 0; r < 4; ++r) {
                const float z   = acc[0][nt][r] + bb[r];
                const float a   = fast_tanh(z);
                const float sN  = 1.0f - a * a;
                const float zd  = acc[1][nt][r];
                const float zdd = acc[2][nt][r];
                const float ad  = sN * zd;
                const float add = fmaf(sN, zdd, -2.0f * a * ad * zd);
                hv[0][r] = (_Float16)a;
                hv[1][r] = (_Float16)ad;
                hv[2][r] = (_Float16)add;
            }
            const int base = ml * 256 + gsw;
            *(half4*)&Ahi[base]        = hv[0];
            *(half4*)&Ahi[4096 + base] = hv[1];
            *(half4*)&Ahi[8192 + base] = hv[2];
        }
    };

    auto E3_PHASE = [&]() {
        float pd[3] = {0.f, 0.f, 0.f};
        #pragma unroll
        for (int nt = 0; nt < 4; ++nt) {
            const int ub = (w4 << 6) + (nt << 4) + u4;
            const f32x4 bb = *(const f32x4*)&b3[ub];
            const f32x4 w4v = *(const f32x4*)&W4[ub];
            #pragma unroll
            for (int r = 0; r < 4; ++r) {
                const float z   = acc[0][nt][r] + bb[r];
                const float a   = fast_tanh(z);
                const float sN  = 1.0f - a * a;
                const float zd  = acc[1][nt][r];
                const float zdd = acc[2][nt][r];
                const float ad  = sN * zd;
                const float add = fmaf(sN, zdd, -2.0f * a * ad * zd);
                pd[0] = fmaf(a,   w4v[r], pd[0]);
                pd[1] = fmaf(ad,  w4v[r], pd[1]);
                pd[2] = fmaf(add, w4v[r], pd[2]);
            }
        }
        #pragma unroll
        for (int s = 0; s < 3; ++s) {
            pd[s] += __shfl_xor(pd[s], 16, 64);
            pd[s] += __shfl_xor(pd[s], 32, 64);
        }
        if (lane < 16) {
            #pragma unroll
            for (int s = 0; s < 3; ++s) psum[grp][w4][s][lane] = pd[s];
        }
    };

    // ======================= staggered slot schedule =========================
    // ---- slot 0: A:L1 ----
    if (!grp) { L1_PHASE(); }
    __syncthreads();

    // ---- slot 1: A:M2 || B:L1 ----
    if (!grp) { MLOOP(W2l); }
    else      { L1_PHASE(); }
    __syncthreads();

    // ---- slot 2: A:E2 || B:M2 ----
    if (!grp) { E2_PHASE(); }
    else      { MLOOP(W2l); }
    __syncthreads();

    // ---- slot 3: A:M3 || B:E2 ----
    if (!grp) { MLOOP(W3l); }
    else      { E2_PHASE(); }
    __syncthreads();

    // ---- slot 4: A:E3 || B:M3+E3 ----
    if (!grp) { E3_PHASE(); }
    else      { MLOOP(W3l); E3_PHASE(); }
    __syncthreads();

    if (tid < 96) {
        const int s  = tid >> 5;         // 0:u 1:du 2:d2u
        const int m  = tid & 31;         // sample within TM=32
        const int t  = m >> 4;           // sub-tile / group
        const int mm = m & 15;
        float v = psum[t][0][s][mm] + psum[t][1][s][mm]
                + psum[t][2][s][mm] + psum[t][3][s][mm];
        if (s == 0) v += b4[0];
        out[(size_t)s * B + blockIdx.x * TM + m] = v;
    }
}

extern "C" void kernel_launch(void* const* d_in, const int* in_sizes, int n_in,
                              void* d_out, int out_size, void* d_ws, size_t ws_size,
                              hipStream_t stream) {
    const float* x  = (const float*)d_in[0];
    const float* W1 = (const float*)d_in[1];
    const float* b1 = (const float*)d_in[2];
    const float* W2 = (const float*)d_in[3];
    const float* b2 = (const float*)d_in[4];
    const float* W3 = (const float*)d_in[5];
    const float* b3 = (const float*)d_in[6];
    const float* W4 = (const float*)d_in[7];
    const float* b4 = (const float*)d_in[8];
    float* out = (float*)d_out;

    const int B = in_sizes[0] / 2;      // x is (B, 2)

    prep_w<<<64, 256, 0, stream>>>(W2, W3, (_Float16*)d_ws);
    pinn_mfma<<<B / TM, 512, 0, stream>>>(x, W1, b1, b2, b3, W4, b4,
                                          (const _Float16*)d_ws, out, B);
}

// Round 8
// 180.313 us; speedup vs baseline: 1.0895x; 1.0727x over previous
//
#include <hip/hip_runtime.h>

// PINN fused: u, du/dx0, d2u/dx0^2 of tanh-MLP (2->256->256->256->1), fp32 in/out.
// Round 14: attack the graded-metric gap, not the dispatch. Every round shows
// bench dur_us - pinn dispatch ~= 49-64us = prep_w + launch overhead. prep_w
// (64 blocks, 8x 1KB-strided scalar loads/thread) is a pure latency chain on a
// 25%-occupied machine; its data volume is 0.1us of BW. Rewrite it transposed:
// one coalesced f32x4 read + 4 scattered u16 stores per thread, 128 blocks.
// pinn_mfma is byte-identical to R7 (best verified dispatch: 123-126us;
// R8 prefetch / R9 occupancy / R12 SGB / R13 stagger all neutral-or-worse,
// so the R7 structure is the established per-dispatch floor).

#define HID 256
#define TM  32

typedef _Float16 half8 __attribute__((ext_vector_type(8)));
typedef _Float16 half4 __attribute__((ext_vector_type(4)));
typedef float    f32x4 __attribute__((ext_vector_type(4)));

#define MFMA16 __builtin_amdgcn_mfma_f32_16x16x32_f16

__device__ __forceinline__ float fast_tanh(float z) {
    // tanh(z) = 1 - 2/(exp(2z)+1); saturates correctly at +-inf
    const float e = __expf(2.0f * z);
#if __has_builtin(__builtin_amdgcn_rcpf)
    const float r = __builtin_amdgcn_rcpf(e + 1.0f);
#else
    const float r = 1.0f / (e + 1.0f);
#endif
    return fmaf(-2.0f, r, 1.0f);
}

// Pack W2/W3 (fp32 [256][256], row=k, col=n) into MFMA A-fragment order for
// W^T, fp16. Fragment layout (unchanged from R7):
//   elem = ((kc*16 + strip)*64 + lane)*8 + j
//   value = W[kc*32 + (lane>>4)*8 + j][strip*16 + (lane&15)]
// ws layout (f16 elems): W2 @ 0, W3 @ 65536. (256KB total)
// NEW direction: thread owns one f32x4 of a W ROW (coalesced read), scatters
// 4 u16 stores. Verified mapping: row = kc*32 + hi*8 + j; col = strip*16 + ml;
// dst = ((kc*16+strip)*64 + hi*16 + ml)*8 + j.
__global__ __launch_bounds__(256) void prep_w(const float* __restrict__ W2,
                                              const float* __restrict__ W3,
                                              _Float16* __restrict__ wsf) {
    const int t = blockIdx.x * 256 + threadIdx.x;     // 0..32767
    const float* __restrict__ W = (t >> 14) ? W3 : W2;
    _Float16* __restrict__ dst = wsf + (size_t)(t >> 14) * 65536;
    const int r    = t & 16383;        // 16384 threads per layer = 256x256/4
    const int row  = r >> 6;           // 0..255
    const int col0 = (r & 63) << 2;    // 0,4,...,252
    const f32x4 v = *(const f32x4*)&W[(size_t)row * HID + col0];
    const int kc = row >> 5;
    const int hi = (row >> 3) & 3;
    const int j  = row & 7;
    #pragma unroll
    for (int c = 0; c < 4; ++c) {
        const int col   = col0 + c;
        const int strip = col >> 4;
        const int ml    = col & 15;
        dst[((size_t)((kc * 16 + strip) * 64 + hi * 16 + ml) << 3) + j] =
            (_Float16)v[c];
    }
}

__global__ __launch_bounds__(256, 2) void pinn_mfma(
    const float* __restrict__ x,
    const float* __restrict__ W1, const float* __restrict__ b1,
    const float* __restrict__ b2, const float* __restrict__ b3,
    const float* __restrict__ W4, const float* __restrict__ b4,
    const _Float16* __restrict__ wsf,
    float* __restrict__ out, int B)
{
    // A-tile: 3 streams x 32 rows x 256 elems fp16, 16B-granule XOR-swizzle:
    // elem(s,row,e) stored at s*8192 + row*256 + (((e>>3) ^ (row&7))<<3) + (e&7)
    __shared__ __align__(16) _Float16 Ahi[3 * 32 * 256];   // 48 KB
    __shared__ float psumW[4][3][TM];                      // 1.5 KB

    const int tid  = threadIdx.x;
    const int s0   = blockIdx.x * TM;
    const int lane = tid & 63;
    const int wave = tid >> 6;          // 0..3

    // ---------- Layer 1: thread owns sample m, 32 consecutive units ----------
    // m mapped so m&7 == tid&7 (conflict-free swizzled writes in 8-lane groups)
    {
        const int m  = (tid & 7) | (((tid >> 3) & 3) << 3);   // 0..31
        const int k0 = (tid >> 5) << 5;                       // 0,32,...,224
        const float2 xv = *(const float2*)&x[(size_t)(s0 + m) * 2];
        const float x0 = xv.x, x1 = xv.y;
        half8 vh[3][4];
        #pragma unroll
        for (int q = 0; q < 4; ++q) {
            #pragma unroll
            for (int h = 0; h < 2; ++h) {
                const int n = k0 + q * 8 + h * 4;
                const f32x4 w0 = *(const f32x4*)&W1[n];
                const f32x4 w1 = *(const f32x4*)&W1[HID + n];
                const f32x4 bb = *(const f32x4*)&b1[n];
                #pragma unroll
                for (int r = 0; r < 4; ++r) {
                    const float z  = fmaf(x0, w0[r], fmaf(x1, w1[r], bb[r]));
                    const float a  = fast_tanh(z);
                    const float sN = 1.0f - a * a;
                    const float ad  = sN * w0[r];
                    const float add = -2.0f * a * ad * w0[r];
                    vh[0][q][h * 4 + r] = (_Float16)a;
                    vh[1][q][h * 4 + r] = (_Float16)ad;
                    vh[2][q][h * 4 + r] = (_Float16)add;
                }
            }
        }
        const int rkm = m & 7;
        const int g0  = k0 >> 3;          // granule base 4*(tid>>5)
        #pragma unroll
        for (int s = 0; s < 3; ++s)
            #pragma unroll
            for (int q = 0; q < 4; ++q)
                *(half8*)&Ahi[s * 8192 + m * 256 + (((g0 + q) ^ rkm) << 3)] = vh[s][q];
    }
    __syncthreads();

    const int ml = lane & 15;            // MFMA B/D col = sample (within 16-tile)
    const int hi = lane >> 4;            // 0..3
    const int rk = ml & 7;               // swizzle key (= row&7 for any mt)
    const int u4 = hi << 2;              // D-row sub-offset (unit)
    const _Float16* __restrict__ Arow = &Ahi[ml * 256];

    #pragma unroll 1
    for (int layer = 0; layer < 2; ++layer) {
        // per-wave weight base: + kc*8192 + nt*512 elems
        const _Float16* __restrict__ Wl =
            wsf + ((size_t)layer << 16) + (wave << 11) + (lane << 3);

        f32x4 acc[3][4][2];              // [stream][nt][mt]
        #pragma unroll
        for (int s = 0; s < 3; ++s)
            #pragma unroll
            for (int nt = 0; nt < 4; ++nt)
                #pragma unroll
                for (int mt = 0; mt < 2; ++mt)
                    acc[s][nt][mt] = (f32x4){0.f, 0.f, 0.f, 0.f};

        #pragma unroll 1
        for (int kc = 0; kc < 8; ++kc) {
            // prefetch next kc's weight frags (kc=7 reloads itself; L2-hot, safe)
            const int kn = (kc < 7) ? kc + 1 : 7;
            const _Float16* __restrict__ Wk = Wl + (kn << 13);
            half8 wnxt[4];
            #pragma unroll
            for (int nt = 0; nt < 4; ++nt)
                wnxt[nt] = *(const half8*)&Wk[nt << 9];

            // A fragments: one vaddr + imm offsets (s*8192 + mt*4096 elems)
            const _Float16* __restrict__ Ap =
                Arow + ((((kc << 2) | hi) ^ rk) << 3);
            half8 af[3][2];
            #pragma unroll
            for (int s = 0; s < 3; ++s)
                #pragma unroll
                for (int mt = 0; mt < 2; ++mt)
                    af[s][mt] = *(const half8*)&Ap[s * 8192 + mt * 4096];

            const _Float16* __restrict__ Wc = Wl + (kc << 13);
            half8 wf[4];
            #pragma unroll
            for (int nt = 0; nt < 4; ++nt)
                wf[nt] = *(const half8*)&Wc[nt << 9];

            __builtin_amdgcn_s_setprio(1);
            #pragma unroll
            for (int nt = 0; nt < 4; ++nt)
                #pragma unroll
                for (int mt = 0; mt < 2; ++mt) {
                    acc[0][nt][mt] = MFMA16(wf[nt], af[0][mt], acc[0][nt][mt], 0, 0, 0);
                    acc[1][nt][mt] = MFMA16(wf[nt], af[1][mt], acc[1][nt][mt], 0, 0, 0);
                    acc[2][nt][mt] = MFMA16(wf[nt], af[2][mt], acc[2][nt][mt], 0, 0, 0);
                }
            __builtin_amdgcn_s_setprio(0);
            (void)wnxt;
        }

        __syncthreads();   // all waves done reading A before overwrite / reuse

        if (layer == 0) {
            // ----- layer-2 epilogue: tanh chain, quantize fp16, swizzled write -----
            #pragma unroll
            for (int nt = 0; nt < 4; ++nt) {
                const int ub  = (wave << 6) + (nt << 4) + u4;   // 4 consecutive units
                const f32x4 bb = *(const f32x4*)&b2[ub];
                const int gsw = (((ub >> 3) ^ rk) << 3) + (u4 & 4);
                #pragma unroll
                for (int mt = 0; mt < 2; ++mt) {
                    half4 hv[3];
                    #pragma unroll
                    for (int r = 0; r < 4; ++r) {
                        const float z   = acc[0][nt][mt][r] + bb[r];
                        const float a   = fast_tanh(z);
                        const float sN  = 1.0f - a * a;
                        const float zd  = acc[1][nt][mt][r];
                        const float zdd = acc[2][nt][mt][r];
                        const float ad  = sN * zd;
                        const float add = fmaf(sN, zdd, -2.0f * a * ad * zd);
                        hv[0][r] = (_Float16)a;
                        hv[1][r] = (_Float16)ad;
                        hv[2][r] = (_Float16)add;
                    }
                    const int base = (mt * 16 + ml) * 256 + gsw;
                    *(half4*)&Ahi[base]         = hv[0];
                    *(half4*)&Ahi[8192  + base] = hv[1];
                    *(half4*)&Ahi[16384 + base] = hv[2];
                }
            }
            __syncthreads();
        } else {
            // ----- layer-3 epilogue fused with W4 dot: all in registers (fp32) -----
            float pd[3][2] = {{0.f, 0.f}, {0.f, 0.f}, {0.f, 0.f}};
            #pragma unroll
            for (int nt = 0; nt < 4; ++nt) {
                const int ub = (wave << 6) + (nt << 4) + u4;
                const f32x4 bb = *(const f32x4*)&b3[ub];
                const f32x4 w4 = *(const f32x4*)&W4[ub];
                #pragma unroll
                for (int mt = 0; mt < 2; ++mt) {
                    #pragma unroll
                    for (int r = 0; r < 4; ++r) {
                        const float z   = acc[0][nt][mt][r] + bb[r];
                        const float a   = fast_tanh(z);
                        const float sN  = 1.0f - a * a;
                        const float zd  = acc[1][nt][mt][r];
                        const float zdd = acc[2][nt][mt][r];
                        const float ad  = sN * zd;
                        const float add = fmaf(sN, zdd, -2.0f * a * ad * zd);
                        pd[0][mt] = fmaf(a,   w4[r], pd[0][mt]);
                        pd[1][mt] = fmaf(ad,  w4[r], pd[1][mt]);
                        pd[2][mt] = fmaf(add, w4[r], pd[2][mt]);
                    }
                }
            }
            // butterfly over lanes {ml, ml+16, ml+32, ml+48}
            #pragma unroll
            for (int s = 0; s < 3; ++s)
                #pragma unroll
                for (int mt = 0; mt < 2; ++mt) {
                    pd[s][mt] += __shfl_xor(pd[s][mt], 16, 64);
                    pd[s][mt] += __shfl_xor(pd[s][mt], 32, 64);
                }
            if (lane < 16) {
                #pragma unroll
                for (int s = 0; s < 3; ++s) {
                    psumW[wave][s][lane]      = pd[s][0];
                    psumW[wave][s][16 + lane] = pd[s][1];
                }
            }
        }
    }
    __syncthreads();

    if (tid < 96) {
        const int s = tid >> 5;          // 0:u 1:du 2:d2u
        const int m = tid & 31;
        const float v = psumW[0][s][m] + psumW[1][s][m]
                      + psumW[2][s][m] + psumW[3][s][m]
                      + ((s == 0) ? b4[0] : 0.0f);
        out[(size_t)s * B + s0 + m] = v;
    }
}

extern "C" void kernel_launch(void* const* d_in, const int* in_sizes, int n_in,
                              void* d_out, int out_size, void* d_ws, size_t ws_size,
                              hipStream_t stream) {
    const float* x  = (const float*)d_in[0];
    const float* W1 = (const float*)d_in[1];
    const float* b1 = (const float*)d_in[2];
    const float* W2 = (const float*)d_in[3];
    const float* b2 = (const float*)d_in[4];
    const float* W3 = (const float*)d_in[5];
    const float* b3 = (const float*)d_in[6];
    const float* W4 = (const float*)d_in[7];
    const float* b4 = (const float*)d_in[8];
    float* out = (float*)d_out;

    const int B = in_sizes[0] / 2;      // x is (B, 2)

    prep_w<<<128, 256, 0, stream>>>(W2, W3, (_Float16*)d_ws);
    pinn_mfma<<<B / TM, 256, 0, stream>>>(x, W1, b1, b2, b3, W4, b4,
                                          (const _Float16*)d_ws, out, B);
}